// Round 8
// baseline (360.203 us; speedup 1.0000x reference)
//
#include <hip/hip_runtime.h>
#include <stdint.h>

#define H_ 128
#define W_ 128
#define HW_ 16384
#define B_ 2
#define XP_ 130  // padded spatial dim (1-px halo)

typedef __attribute__((ext_vector_type(4))) float f32x4;
typedef _Float16 half_t;
typedef __attribute__((ext_vector_type(8))) _Float16 h8v;
typedef __attribute__((ext_vector_type(4))) _Float16 h4v;

__device__ __forceinline__ f32x4 MFMA(h8v a, h8v b, f32x4 c) {
  return __builtin_amdgcn_mfma_f32_16x16x32_f16(a, b, c, 0, 0, 0);
}
__device__ __forceinline__ f32x4 zero4() {
  f32x4 z; z[0] = 0.f; z[1] = 0.f; z[2] = 0.f; z[3] = 0.f; return z;
}
__device__ __forceinline__ h8v splat8(half_t x) {
  h8v v;
#pragma unroll
  for (int j = 0; j < 8; ++j) v[j] = x;
  return v;
}
// Swizzled LDS offset (element units). Tiles are [rows][64] fp16 (128B rows).
__device__ __forceinline__ int swz(int r, int c8) {
  return r * 64 + ((c8 ^ (r & 7)) << 3);
}

template <int N>
__device__ __forceinline__ void s_wait_vmcnt() {
  asm volatile("s_waitcnt vmcnt(%0)" ::"n"(N) : "memory");
}

// global->LDS DMA, 16B per lane. Dest must be wave-uniform base + lane*16.
typedef const __attribute__((address_space(1))) uint32_t glb_u32;
typedef __attribute__((address_space(3))) uint32_t lds_u32;
__device__ __forceinline__ void gl_lds16(const half_t* g, half_t* l) {
  __builtin_amdgcn_global_load_lds((glb_u32*)(uintptr_t)g,
                                   (lds_u32*)(uint32_t)(uintptr_t)l, 16, 0, 0);
}

// ---------- zero the 1-px halos of all three padded NHWC buffers ----------
__global__ __launch_bounds__(256) void zeropad_all(
    half_t* __restrict__ xcat, half_t* __restrict__ h1p,
    half_t* __restrict__ h2p) {
  int idx = blockIdx.x * 256 + threadIdx.x;
  half_t* buf; int C, li;
  if (idx < 99072) { buf = xcat; C = 768; li = idx; }
  else if (idx < 132096) { buf = h1p; C = 256; li = idx - 99072; }
  else if (idx < 165120) { buf = h2p; C = 256; li = idx - 132096; }
  else return;
  int nc = C >> 3;
  int c8 = li % nc;
  int p = li / nc;
  int b = p / 516, i = p % 516;
  int y, x;
  if (i < 130) { y = 0; x = i; }
  else if (i < 260) { y = 129; x = i - 130; }
  else if (i < 388) { y = i - 260 + 1; x = 0; }
  else { y = i - 388 + 1; x = 129; }
  h8v z;
#pragma unroll
  for (int j = 0; j < 8; ++j) z[j] = (half_t)0.f;
  *(h8v*)(buf + ((size_t)(b * XP_ + y) * XP_ + x) * C + c8 * 8) = z;
}

// ---------- pack: three fp32 NCHW -> one fp16 padded NHWC (B,130,130,768) ----------
__global__ __launch_bounds__(256) void pack_x(
    const float* __restrict__ f1, const float* __restrict__ f2,
    const float* __restrict__ f3, half_t* __restrict__ xcat) {
  __shared__ float tile[64][65];
  int bid = blockIdx.x;
  int t = bid % 24, by = bid / 24;
  int b = by >> 7, y = by & 127;
  int s = t / 8, t2 = t % 8;
  int x0 = (t2 & 1) * 64, c0 = (t2 >> 1) * 64;
  const float* f = (s == 0) ? f1 : ((s == 1) ? f2 : f3);
  int tid = threadIdx.x;
  int rx = tid & 63, rc = tid >> 6;
  const float* srcp = f + ((size_t)(b * 256 + c0)) * HW_ + (size_t)y * W_ + x0;
#pragma unroll
  for (int i = 0; i < 16; ++i) {
    int c = rc + i * 4;
    tile[c][rx] = srcp[(size_t)c * HW_ + rx];
  }
  __syncthreads();
#pragma unroll
  for (int it = 0; it < 2; ++it) {
    int task = tid + it * 256;
    int x = task & 63, c8 = task >> 6;
    h8v v;
#pragma unroll
    for (int j = 0; j < 8; ++j) v[j] = (half_t)tile[c8 * 8 + j][x];
    size_t pix = (size_t)(b * XP_ + y + 1) * XP_ + x0 + x + 1;
    *(h8v*)(xcat + pix * 768 + s * 256 + c0 + c8 * 8) = v;
  }
}

// ---------- weight transforms (all fused into one launch) ----------
__device__ __forceinline__ void wt_conv(const float* __restrict__ w,
                                        half_t* __restrict__ wt, int CO, int CI,
                                        int idx) {
  int CS = CI >> 6;
  int e = idx & 8191, tile = idx >> 13;
  int task = e >> 3, j = e & 7;
  int r = task >> 3, c8 = (task & 7) ^ (r & 7);
  int tpb = 9 * CS;
  int coblk = tile / tpb, within = tile - coblk * tpb;
  int dx = within % 3, q = within / 3;
  int cs = q % CS, g = q / CS;
  int t = g * 3 + dx;
  int co = coblk * 128 + r;
  int ci = cs * 64 + c8 * 8 + j;
  float v = (co < CO) ? w[((size_t)co * CI + ci) * 9 + t] : 0.f;
  wt[idx] = (half_t)v;
}
__device__ __forceinline__ void wt_c64(const float* __restrict__ w,
                                       half_t* __restrict__ wt, int idx) {
  int e = idx & 4095, tile = idx >> 12;
  int task = e >> 3, j = e & 7;
  int r = task >> 3, c8 = (task & 7) ^ (r & 7);
  int dx = tile % 3, q = tile / 3;
  int cs = q & 3, g = q >> 2;
  int t = g * 3 + dx;
  int ci = cs * 64 + c8 * 8 + j;
  float v = (r < 36) ? w[((size_t)r * 256 + ci) * 9 + t] : 0.f;
  wt[idx] = (half_t)v;
}
__device__ __forceinline__ void wt_256(const float* __restrict__ w,
                                       half_t* __restrict__ wt, int idx) {
  int e = idx & 16383, tile = idx >> 14;
  int task = e >> 3, j = e & 7;
  int r = task >> 3, c8 = (task & 7) ^ (r & 7);
  int cs = tile & 3, t = tile >> 2;
  int ci = cs * 64 + c8 * 8 + j;
  wt[idx] = (half_t)w[((size_t)r * 256 + ci) * 9 + t];
}
__device__ __forceinline__ void wt_fuse(const float* __restrict__ w,
                                        half_t* __restrict__ wt, int idx) {
  int e = idx & 8191, tile = idx >> 13;
  int task = e >> 3, j = e & 7;
  int r = task >> 3, c8 = (task & 7) ^ (r & 7);
  int cs = tile % 12, coblk = tile / 12;
  int co = coblk * 128 + r;
  int ci = cs * 64 + c8 * 8 + j;
  wt[idx] = (half_t)w[(size_t)co * 768 + ci];
}

__global__ __launch_bounds__(256) void wtrans_all(
    const float* __restrict__ w1, half_t* __restrict__ w1t,
    const float* __restrict__ w2, half_t* __restrict__ w2t,
    const float* __restrict__ w3, half_t* __restrict__ w3t,
    const float* __restrict__ wd2, half_t* __restrict__ wd2t,
    const float* __restrict__ wd3, half_t* __restrict__ wd3t,
    const float* __restrict__ wf, half_t* __restrict__ wft) {
  int bid = blockIdx.x, tid = threadIdx.x;
  if (bid < 6912)       wt_conv(w1, w1t, 256, 768, bid * 256 + tid);
  else if (bid < 9216)  wt_conv(w2, w2t, 256, 256, (bid - 6912) * 256 + tid);
  else if (bid < 9792)  wt_c64(w3, w3t, (bid - 9216) * 256 + tid);
  else if (bid < 12096) wt_256(wd2, wd2t, (bid - 9792) * 256 + tid);
  else if (bid < 14400) wt_256(wd3, wd3t, (bid - 12096) * 256 + tid);
  else                  wt_fuse(wf, wft, (bid - 14400) * 256 + tid);
}

// ---------- 3x3 conv, implicit GEMM, act-row sharing + counted vmcnt ----------
template <int CIN, bool RELU>
__global__ __launch_bounds__(256) void conv3x3(
    const half_t* __restrict__ in, const half_t* __restrict__ wt,
    const float* __restrict__ bias, half_t* __restrict__ outb) {
  constexpr int CS = CIN / 64;
  constexpr int NGI = 3 * CS;  // (ky, cs) act-tile count
  __shared__ __align__(16) half_t wl[2][8192];
  __shared__ __align__(16) half_t al[2][8704];  // 136 x 64
  int tid = threadIdx.x;
  int by = blockIdx.x;
  int b = by >> 7, y = by & 127;
  int co0 = blockIdx.y * 128;
  int w = tid >> 6, l = tid & 63, lr = l & 15, lg = l >> 4;
  int wr = (w >> 1) * 64, wc = (w & 1) * 64;
  f32x4 acc[4][4];
#pragma unroll
  for (int i = 0; i < 4; ++i)
#pragma unroll
    for (int j = 0; j < 4; ++j) acc[i][j] = zero4();

  const half_t* wbase = wt + (size_t)blockIdx.y * (9 * CS) * 8192;

  int ldsoff[4], aoff[4], ldsoff4, aoff4;
#pragma unroll
  for (int it = 0; it < 4; ++it) {
    int task = tid + it * 256;
    ldsoff[it] = task * 8;
    int r = task >> 3, c8 = (task & 7) ^ (r & 7);
    aoff[it] = r * CIN + c8 * 8;
  }
  {
    int task = 1024 + tid;
    ldsoff4 = task * 8;
    int r = task >> 3, c8 = (task & 7) ^ (r & 7);
    aoff4 = r * CIN + c8 * 8;
  }

  auto stage_w = [&](int s, int buf) {
    const half_t* wp = wbase + (size_t)s * 8192;
#pragma unroll
    for (int it = 0; it < 4; ++it)
      gl_lds16(wp + ldsoff[it], &wl[buf][ldsoff[it]]);
  };
  auto stage_a = [&](int gi, int buf) {
    int g = gi / CS, cs = gi - g * CS;
    const half_t* ap = in + ((size_t)(b * XP_ + y + g) * XP_) * CIN + cs * 64;
    if (tid < 64) gl_lds16(ap + aoff4, &al[buf][ldsoff4]);
#pragma unroll
    for (int it = 0; it < 4; ++it)
      gl_lds16(ap + aoff[it], &al[buf][ldsoff[it]]);
  };
  auto compute = [&](int dx, int wbuf, int abuf) {
    const half_t* wb = wl[wbuf];
    const half_t* ab = al[abuf];
    h8v af[4][2], bf[4][2];
#pragma unroll
    for (int cg = 0; cg < 4; ++cg)
#pragma unroll
      for (int kc = 0; kc < 2; ++kc)
        af[cg][kc] = *(const h8v*)(wb + swz(wr + 16 * cg + lr, 4 * kc + lg));
#pragma unroll
    for (int pg = 0; pg < 4; ++pg)
#pragma unroll
      for (int kc = 0; kc < 2; ++kc)
        bf[pg][kc] = *(const h8v*)(ab + swz(wc + 16 * pg + lr + dx, 4 * kc + lg));
    __builtin_amdgcn_s_setprio(1);
#pragma unroll
    for (int cg = 0; cg < 4; ++cg)
#pragma unroll
      for (int pg = 0; pg < 4; ++pg) {
        acc[cg][pg] = MFMA(af[cg][0], bf[pg][0], acc[cg][pg]);
        acc[cg][pg] = MFMA(af[cg][1], bf[pg][1], acc[cg][pg]);
      }
    __builtin_amdgcn_s_setprio(0);
  };

  stage_w(0, 0);
  stage_a(0, 0);
  for (int gi = 0; gi < NGI; ++gi) {
    int abuf = gi & 1;
    int s0 = 3 * gi;
    stage_w(s0 + 1, (s0 + 1) & 1);
    s_wait_vmcnt<4>();
    __builtin_amdgcn_s_barrier();
    compute(0, s0 & 1, abuf);
    __builtin_amdgcn_s_barrier();
    stage_w(s0 + 2, s0 & 1);
    s_wait_vmcnt<4>();
    __builtin_amdgcn_s_barrier();
    compute(1, (s0 + 1) & 1, abuf);
    __builtin_amdgcn_s_barrier();
    if (gi + 1 < NGI) {
      stage_w(s0 + 3, (s0 + 3) & 1);
      stage_a(gi + 1, abuf ^ 1);
      s_wait_vmcnt<8>();
    } else {
      s_wait_vmcnt<0>();
    }
    __builtin_amdgcn_s_barrier();
    compute(2, s0 & 1, abuf);
    __builtin_amdgcn_s_barrier();
  }
#pragma unroll
  for (int cg = 0; cg < 4; ++cg) {
    int co = co0 + wr + 16 * cg + 4 * lg;
    f32x4 bv = *(const f32x4*)(bias + co);
#pragma unroll
    for (int pg = 0; pg < 4; ++pg) {
      int px = wc + 16 * pg + lr;
      f32x4 v = acc[cg][pg];
#pragma unroll
      for (int r = 0; r < 4; ++r) {
        v[r] += bv[r];
        if (RELU) v[r] = fmaxf(v[r], 0.f);
      }
      size_t pix = (size_t)(b * XP_ + y + 1) * XP_ + px + 1;
      h4v pv;
#pragma unroll
      for (int r = 0; r < 4; ++r) pv[r] = (half_t)v[r];
      *(h4v*)(outb + pix * 256 + co) = pv;
    }
  }
}

// ---------- narrow 3x3 conv for the 36-co offset head (fp32 NHWC out) ----------
__global__ __launch_bounds__(256) void conv3_c64(
    const half_t* __restrict__ in, const half_t* __restrict__ wt,
    const float* __restrict__ bias, float* __restrict__ outf) {
  constexpr int CIN = 256, CS = 4, NGI = 12;
  __shared__ __align__(16) half_t wl[2][4096];
  __shared__ __align__(16) half_t al[2][8704];
  int tid = threadIdx.x;
  int by = blockIdx.x;
  int b = by >> 7, y = by & 127;
  int w = tid >> 6, l = tid & 63, lr = l & 15, lg = l >> 4;
  int wc = w * 32;
  f32x4 acc[4][2];
#pragma unroll
  for (int i = 0; i < 4; ++i)
#pragma unroll
    for (int j = 0; j < 2; ++j) acc[i][j] = zero4();

  int ldsW[2];
#pragma unroll
  for (int it = 0; it < 2; ++it) ldsW[it] = (tid + it * 256) * 8;
  int ldsoff[4], aoff[4], ldsoff4, aoff4;
#pragma unroll
  for (int it = 0; it < 4; ++it) {
    int task = tid + it * 256;
    ldsoff[it] = task * 8;
    int r = task >> 3, c8 = (task & 7) ^ (r & 7);
    aoff[it] = r * CIN + c8 * 8;
  }
  {
    int task = 1024 + tid;
    ldsoff4 = task * 8;
    int r = task >> 3, c8 = (task & 7) ^ (r & 7);
    aoff4 = r * CIN + c8 * 8;
  }

  auto stage_w = [&](int s, int buf) {
    const half_t* wp = wt + (size_t)s * 4096;
#pragma unroll
    for (int it = 0; it < 2; ++it)
      gl_lds16(wp + ldsW[it], &wl[buf][ldsW[it]]);
  };
  auto stage_a = [&](int gi, int buf) {
    int g = gi / CS, cs = gi - g * CS;
    const half_t* ap = in + ((size_t)(b * XP_ + y + g) * XP_) * CIN + cs * 64;
    if (tid < 64) gl_lds16(ap + aoff4, &al[buf][ldsoff4]);
#pragma unroll
    for (int it = 0; it < 4; ++it)
      gl_lds16(ap + aoff[it], &al[buf][ldsoff[it]]);
  };
  auto compute = [&](int dx, int wbuf, int abuf) {
    const half_t* wb = wl[wbuf];
    const half_t* ab = al[abuf];
    h8v af[4][2], bf[2][2];
#pragma unroll
    for (int cg = 0; cg < 4; ++cg)
#pragma unroll
      for (int kc = 0; kc < 2; ++kc)
        af[cg][kc] = *(const h8v*)(wb + swz(16 * cg + lr, 4 * kc + lg));
#pragma unroll
    for (int pg = 0; pg < 2; ++pg)
#pragma unroll
      for (int kc = 0; kc < 2; ++kc)
        bf[pg][kc] = *(const h8v*)(ab + swz(wc + 16 * pg + lr + dx, 4 * kc + lg));
    __builtin_amdgcn_s_setprio(1);
#pragma unroll
    for (int cg = 0; cg < 4; ++cg)
#pragma unroll
      for (int pg = 0; pg < 2; ++pg) {
        acc[cg][pg] = MFMA(af[cg][0], bf[pg][0], acc[cg][pg]);
        acc[cg][pg] = MFMA(af[cg][1], bf[pg][1], acc[cg][pg]);
      }
    __builtin_amdgcn_s_setprio(0);
  };

  stage_w(0, 0);
  stage_a(0, 0);
  for (int gi = 0; gi < NGI; ++gi) {
    int abuf = gi & 1;
    int s0 = 3 * gi;
    stage_w(s0 + 1, (s0 + 1) & 1);
    s_wait_vmcnt<2>();
    __builtin_amdgcn_s_barrier();
    compute(0, s0 & 1, abuf);
    __builtin_amdgcn_s_barrier();
    stage_w(s0 + 2, s0 & 1);
    s_wait_vmcnt<2>();
    __builtin_amdgcn_s_barrier();
    compute(1, (s0 + 1) & 1, abuf);
    __builtin_amdgcn_s_barrier();
    if (gi + 1 < NGI) {
      stage_w(s0 + 3, (s0 + 3) & 1);
      stage_a(gi + 1, abuf ^ 1);
      s_wait_vmcnt<6>();
    } else {
      s_wait_vmcnt<0>();
    }
    __builtin_amdgcn_s_barrier();
    compute(2, s0 & 1, abuf);
    __builtin_amdgcn_s_barrier();
  }
#pragma unroll
  for (int cg = 0; cg < 4; ++cg) {
    int co = 16 * cg + 4 * lg;
    if (co >= 36) continue;
    f32x4 bv = *(const f32x4*)(bias + co);
#pragma unroll
    for (int pg = 0; pg < 2; ++pg) {
      int px = wc + 16 * pg + lr;
      f32x4 v = acc[cg][pg];
#pragma unroll
      for (int r = 0; r < 4; ++r) v[r] += bv[r];
      size_t pix = (size_t)(b * H_ + y) * W_ + px;
      *(f32x4*)(outf + pix * 36 + co) = v;
    }
  }
}

// ---------- deformable conv: 256-thread blocks, co-split halves ----------
// grid (256 rows, 4): y = head*2 + cohalf. Each block: 128co x 128px, 4 waves
// as 2x2 (64co x 64px, acc[4][4]). LDS 70KB -> 2 independent blocks/CU, which
// desynchronizes barrier stalls (r6 schedule: dbuf weights, 1 barrier/step).
__global__ __launch_bounds__(256) void dcn(
    const half_t* __restrict__ xcat, const float* __restrict__ off,
    const half_t* __restrict__ wt2, const half_t* __restrict__ wt3,
    half_t* __restrict__ out2, half_t* __restrict__ out3) {
  __shared__ __align__(16) half_t wl[2][8192];
  __shared__ __align__(16) half_t al[2][8192];
  __shared__ int caddr[2][128][4];
  __shared__ half_t chw[2][128][4];
  int gy = blockIdx.y;
  int head = gy >> 1, cohalf = gy & 1;
  const half_t* wt = head ? wt3 : wt2;
  half_t* outb = head ? out3 : out2;
  int cbase = 256 + (head << 8);
  int obase = 18 * head;
  int tid = threadIdx.x;
  int bx = blockIdx.x;
  int by = ((bx & 7) << 5) | (bx >> 3);  // XCD-chunked (256 % 8 == 0, bijective)
  int b = by >> 7, y = by & 127;
  int w = tid >> 6, l = tid & 63, lr = l & 15, lg = l >> 4;
  int wr = (w >> 1) * 64, wc = (w & 1) * 64;
  size_t rowpix = (size_t)(b * H_ + y) * W_;
  f32x4 acc[4][4];
#pragma unroll
  for (int i = 0; i < 4; ++i)
#pragma unroll
    for (int j = 0; j < 4; ++j) acc[i][j] = zero4();

  // this co-half's 128 rows start at +8192 elements within each 16K tile
  const half_t* wbase = wt + cohalf * 8192;

  auto coeffs = [&](int t) {  // writes coeff buffer [t&1]; caller barriers
    if (tid < 128) {
      int px = tid;
      const float* op = off + (rowpix + px) * 36 + obase + 2 * t;
      float dy = op[0], dx = op[1];
      float ysf = (float)(y + (t / 3) - 1) + dy;
      float xsf = (float)(px + (t % 3) - 1) + dx;
      float y0f = floorf(ysf), x0f = floorf(xsf);
      float fy = ysf - y0f, fx = xsf - x0f;
      int y0 = (int)y0f, x0 = (int)x0f;
#pragma unroll
      for (int c = 0; c < 4; ++c) {
        int iy = y0 + (c >> 1), ix = x0 + (c & 1);
        float wc2 = ((c >> 1) ? fy : 1.f - fy) * ((c & 1) ? fx : 1.f - fx);
        bool valid = (iy >= 0) && (iy < H_) && (ix >= 0) && (ix < W_);
        int cy = iy < 0 ? 0 : (iy > H_ - 1 ? H_ - 1 : iy);
        int cx = ix < 0 ? 0 : (ix > W_ - 1 ? W_ - 1 : ix);
        caddr[t & 1][px][c] = ((b * XP_ + cy + 1) * XP_ + cx + 1) * 768 + cbase;
        chw[t & 1][px][c] = (half_t)(valid ? wc2 : 0.f);
      }
    }
  };

  h8v cv[4][4];  // prefetched corner values (static indexing only)
  auto blendload = [&](int s) {
    int t = (s >> 2) & 1;
    int c0 = (s & 3) * 64;
#pragma unroll
    for (int it = 0; it < 4; ++it) {
      int task = tid + it * 256;
      int px = task >> 3;
      int cc = c0 + (task & 7) * 8;
#pragma unroll
      for (int c = 0; c < 4; ++c)
        cv[it][c] = *(const h8v*)(xcat + caddr[t][px][c] + cc);
    }
  };
  auto blendwrite = [&](int s, int buf) {
    int t = (s >> 2) & 1;
#pragma unroll
    for (int it = 0; it < 4; ++it) {
      int task = tid + it * 256;
      int px = task >> 3, c8 = task & 7;
      h8v av = cv[it][0] * splat8(chw[t][px][0]);
      av += cv[it][1] * splat8(chw[t][px][1]);
      av += cv[it][2] * splat8(chw[t][px][2]);
      av += cv[it][3] * splat8(chw[t][px][3]);
      *(h8v*)(&al[buf][swz(px, c8)]) = av;
    }
  };
  auto stagew = [&](int s, int buf) {
    const half_t* wp = wbase + (size_t)s * 16384;
#pragma unroll
    for (int it = 0; it < 4; ++it) {
      int task = tid + it * 256;
      gl_lds16(wp + task * 8, &wl[buf][task * 8]);
    }
  };

  coeffs(0);
  __syncthreads();
  stagew(0, 0);
  blendload(0);
  blendwrite(0, 0);  // cv wait also retires stagew(0) (issued first)
  __syncthreads();
  for (int s = 0; s < 36; ++s) {
    int cur = s & 1, nxt = cur ^ 1;
    if (s + 1 < 36) {
      stagew(s + 1, nxt);   // DMA in flight across the MFMAs
      blendload(s + 1);     // corner gathers in flight across the MFMAs
    }
    if ((s & 3) == 0 && (s >> 2) + 1 < 9) coeffs((s >> 2) + 1);  // other parity
    const half_t* wb = wl[cur];
    const half_t* ab = al[cur];
    h8v af[4][2], bf[4][2];
#pragma unroll
    for (int cg = 0; cg < 4; ++cg)
#pragma unroll
      for (int kc = 0; kc < 2; ++kc)
        af[cg][kc] = *(const h8v*)(wb + swz(wr + 16 * cg + lr, 4 * kc + lg));
#pragma unroll
    for (int pg = 0; pg < 4; ++pg)
#pragma unroll
      for (int kc = 0; kc < 2; ++kc)
        bf[pg][kc] = *(const h8v*)(ab + swz(wc + 16 * pg + lr, 4 * kc + lg));
    __builtin_amdgcn_s_setprio(1);
#pragma unroll
    for (int cg = 0; cg < 4; ++cg)
#pragma unroll
      for (int pg = 0; pg < 4; ++pg) {
        acc[cg][pg] = MFMA(af[cg][0], bf[pg][0], acc[cg][pg]);
        acc[cg][pg] = MFMA(af[cg][1], bf[pg][1], acc[cg][pg]);
      }
    __builtin_amdgcn_s_setprio(0);
    if (s + 1 < 36) blendwrite(s + 1, nxt);
    __syncthreads();
  }
#pragma unroll
  for (int cg = 0; cg < 4; ++cg) {
    int co = cohalf * 128 + wr + 16 * cg + 4 * lg;
#pragma unroll
    for (int pg = 0; pg < 4; ++pg) {
      int px = wc + 16 * pg + lr;
      size_t pix = rowpix + px;
      f32x4 v = acc[cg][pg];
      h4v pv;
#pragma unroll
      for (int r = 0; r < 4; ++r) pv[r] = (half_t)v[r];
      *(h4v*)(outb + pix * 256 + co) = pv;
    }
  }
}

// ---------- 1x1 fuse conv: 2-phase + counted vmcnt, out fp32 NCHW ----------
__global__ __launch_bounds__(256) void fuse1x1(
    const half_t* __restrict__ xcat, const half_t* __restrict__ al2,
    const half_t* __restrict__ al3, const half_t* __restrict__ wt,
    const float* __restrict__ bias, float* __restrict__ out) {
  __shared__ __align__(16) half_t wl[2][8192];
  __shared__ __align__(16) half_t al[2][8192];
  int tid = threadIdx.x;
  int by = blockIdx.x;
  int b = by >> 7, y = by & 127;
  int co0 = blockIdx.y * 128;
  int w = tid >> 6, l = tid & 63, lr = l & 15, lg = l >> 4;
  int pxb = (w >> 1) * 64, cob = (w & 1) * 64;
  f32x4 acc[4][4];  // [pg][cg]
#pragma unroll
  for (int i = 0; i < 4; ++i)
#pragma unroll
    for (int j = 0; j < 4; ++j) acc[i][j] = zero4();

  const half_t* wbase = wt + (size_t)blockIdx.y * 12 * 8192;
  size_t rowpix = (size_t)(b * H_ + y) * W_;
  const half_t* xrow = xcat + ((size_t)(b * XP_ + y + 1) * XP_ + 1) * 768;

  int woff[4], rr[4], c8x8[4];
#pragma unroll
  for (int it = 0; it < 4; ++it) {
    int task = tid + it * 256;
    woff[it] = task * 8;
    rr[it] = task >> 3;
    c8x8[it] = (((task & 7) ^ (rr[it] & 7))) * 8;
  }

  auto stage = [&](int cs, int buf) {
    const half_t* wp = wbase + (size_t)cs * 8192;
#pragma unroll
    for (int it = 0; it < 4; ++it) gl_lds16(wp + woff[it], &wl[buf][woff[it]]);
#pragma unroll
    for (int it = 0; it < 4; ++it) {
      int kk = cs * 64 + c8x8[it];
      const half_t* sp;
      if (kk < 256) sp = xrow + (size_t)rr[it] * 768 + kk;
      else if (kk < 512) sp = al2 + (rowpix + rr[it]) * 256 + (kk - 256);
      else sp = al3 + (rowpix + rr[it]) * 256 + (kk - 512);
      gl_lds16(sp, &al[buf][woff[it]]);
    }
  };

  stage(0, 0);
  for (int cs = 0; cs < 12; ++cs) {
    int cur = cs & 1;
    if (cs + 1 < 12) {
      stage(cs + 1, cur ^ 1);
      s_wait_vmcnt<8>();
    } else {
      s_wait_vmcnt<0>();
    }
    __builtin_amdgcn_s_barrier();
    const half_t* wb = wl[cur];
    const half_t* ab = al[cur];
    h8v af[4][2], bf[4][2];
#pragma unroll
    for (int pg = 0; pg < 4; ++pg)
#pragma unroll
      for (int kc = 0; kc < 2; ++kc)
        af[pg][kc] = *(const h8v*)(ab + swz(pxb + 16 * pg + lr, 4 * kc + lg));
#pragma unroll
    for (int cg = 0; cg < 4; ++cg)
#pragma unroll
      for (int kc = 0; kc < 2; ++kc)
        bf[cg][kc] = *(const h8v*)(wb + swz(cob + 16 * cg + lr, 4 * kc + lg));
    __builtin_amdgcn_s_setprio(1);
#pragma unroll
    for (int pg = 0; pg < 4; ++pg)
#pragma unroll
      for (int cg = 0; cg < 4; ++cg) {
        acc[pg][cg] = MFMA(af[pg][0], bf[cg][0], acc[pg][cg]);
        acc[pg][cg] = MFMA(af[pg][1], bf[cg][1], acc[pg][cg]);
      }
    __builtin_amdgcn_s_setprio(0);
    __builtin_amdgcn_s_barrier();
  }
#pragma unroll
  for (int pg = 0; pg < 4; ++pg)
#pragma unroll
    for (int cg = 0; cg < 4; ++cg) {
      int px = pxb + 16 * pg + 4 * lg;
      int co = co0 + cob + 16 * cg + lr;
      float bb = bias[co];
      f32x4 v = acc[pg][cg];
#pragma unroll
      for (int r = 0; r < 4; ++r) v[r] += bb;
      *(f32x4*)(out + ((size_t)(b * 256 + co)) * HW_ + (size_t)y * W_ + px) = v;
    }
}

extern "C" void kernel_launch(void* const* d_in, const int* in_sizes, int n_in,
                              void* d_out, int out_size, void* d_ws, size_t ws_size,
                              hipStream_t stream) {
  (void)in_sizes; (void)n_in; (void)out_size; (void)ws_size;
  const float* ft1 = (const float*)d_in[0];
  const float* ft2 = (const float*)d_in[1];
  const float* ft3 = (const float*)d_in[2];
  const float* w1 = (const float*)d_in[3];
  const float* b1 = (const float*)d_in[4];
  const float* w2 = (const float*)d_in[5];
  const float* b2 = (const float*)d_in[6];
  const float* w3 = (const float*)d_in[7];
  const float* b3 = (const float*)d_in[8];
  const float* wd2 = (const float*)d_in[9];
  const float* wd3 = (const float*)d_in[10];
  const float* wf = (const float*)d_in[11];
  const float* bfu = (const float*)d_in[12];

  char* p = (char*)d_ws;
  half_t* xcat = (half_t*)p; p += (size_t)B_ * XP_ * XP_ * 768 * 2;  // 51.9 MB
  half_t* h1p = (half_t*)p;  p += (size_t)B_ * XP_ * XP_ * 256 * 2;  // 17.3 MB
  half_t* h2p = (half_t*)p;  p += (size_t)B_ * XP_ * XP_ * 256 * 2;  // 17.3 MB
  float* off = (float*)p;    p += (size_t)B_ * HW_ * 36 * 4;         // 4.7 MB
  half_t* w1t = (half_t*)p;  p += (size_t)2 * 9 * 12 * 8192 * 2;
  half_t* w2t = (half_t*)p;  p += (size_t)2 * 9 * 4 * 8192 * 2;
  half_t* w3t = (half_t*)p;  p += (size_t)36 * 4096 * 2;
  half_t* wd2t = (half_t*)p; p += (size_t)36 * 16384 * 2;
  half_t* wd3t = (half_t*)p; p += (size_t)36 * 16384 * 2;
  half_t* wft = (half_t*)p;  p += (size_t)2 * 12 * 8192 * 2;         // ~99.4 MB total
  half_t* al2 = h1p;  // h1p dead after conv2
  half_t* al3 = h2p;  // h2p dead after conv3

  zeropad_all<<<645, 256, 0, stream>>>(xcat, h1p, h2p);
  pack_x<<<24 * B_ * H_, 256, 0, stream>>>(ft1, ft2, ft3, xcat);
  wtrans_all<<<15168, 256, 0, stream>>>(w1, w1t, w2, w2t, w3, w3t,
                                        wd2, wd2t, wd3, wd3t, wf, wft);

  conv3x3<768, true><<<dim3(B_ * H_, 2), 256, 0, stream>>>(xcat, w1t, b1, h1p);
  conv3x3<256, true><<<dim3(B_ * H_, 2), 256, 0, stream>>>(h1p, w2t, b2, h2p);
  conv3_c64<<<dim3(B_ * H_), 256, 0, stream>>>(h2p, w3t, b3, off);
  dcn<<<dim3(B_ * H_, 4), 256, 0, stream>>>(xcat, off, wd2t, wd3t, al2, al3);
  fuse1x1<<<dim3(B_ * H_, 2), 256, 0, stream>>>(xcat, al2, al3, wft, bfu, (float*)d_out);
}

// Round 9
// 321.085 us; speedup vs baseline: 1.1218x; 1.1218x over previous
//
#include <hip/hip_runtime.h>
#include <stdint.h>

#define H_ 128
#define W_ 128
#define HW_ 16384
#define B_ 2
#define XP_ 130  // padded spatial dim (1-px halo)

typedef __attribute__((ext_vector_type(4))) float f32x4;
typedef _Float16 half_t;
typedef __attribute__((ext_vector_type(8))) _Float16 h8v;
typedef __attribute__((ext_vector_type(4))) _Float16 h4v;

__device__ __forceinline__ f32x4 MFMA(h8v a, h8v b, f32x4 c) {
  return __builtin_amdgcn_mfma_f32_16x16x32_f16(a, b, c, 0, 0, 0);
}
__device__ __forceinline__ f32x4 zero4() {
  f32x4 z; z[0] = 0.f; z[1] = 0.f; z[2] = 0.f; z[3] = 0.f; return z;
}
__device__ __forceinline__ h8v splat8(half_t x) {
  h8v v;
#pragma unroll
  for (int j = 0; j < 8; ++j) v[j] = x;
  return v;
}
// Swizzled LDS offset (element units). Tiles are [rows][64] fp16 (128B rows).
__device__ __forceinline__ int swz(int r, int c8) {
  return r * 64 + ((c8 ^ (r & 7)) << 3);
}

template <int N>
__device__ __forceinline__ void s_wait_vmcnt() {
  asm volatile("s_waitcnt vmcnt(%0)" ::"n"(N) : "memory");
}

// global->LDS DMA, 16B per lane. Dest must be wave-uniform base + lane*16.
typedef const __attribute__((address_space(1))) uint32_t glb_u32;
typedef __attribute__((address_space(3))) uint32_t lds_u32;
__device__ __forceinline__ void gl_lds16(const half_t* g, half_t* l) {
  __builtin_amdgcn_global_load_lds((glb_u32*)(uintptr_t)g,
                                   (lds_u32*)(uint32_t)(uintptr_t)l, 16, 0, 0);
}

// ---------- zero the 1-px halos of all three padded NHWC buffers ----------
__global__ __launch_bounds__(256) void zeropad_all(
    half_t* __restrict__ xcat, half_t* __restrict__ h1p,
    half_t* __restrict__ h2p) {
  int idx = blockIdx.x * 256 + threadIdx.x;
  half_t* buf; int C, li;
  if (idx < 99072) { buf = xcat; C = 768; li = idx; }
  else if (idx < 132096) { buf = h1p; C = 256; li = idx - 99072; }
  else if (idx < 165120) { buf = h2p; C = 256; li = idx - 132096; }
  else return;
  int nc = C >> 3;
  int c8 = li % nc;
  int p = li / nc;
  int b = p / 516, i = p % 516;
  int y, x;
  if (i < 130) { y = 0; x = i; }
  else if (i < 260) { y = 129; x = i - 130; }
  else if (i < 388) { y = i - 260 + 1; x = 0; }
  else { y = i - 388 + 1; x = 129; }
  h8v z;
#pragma unroll
  for (int j = 0; j < 8; ++j) z[j] = (half_t)0.f;
  *(h8v*)(buf + ((size_t)(b * XP_ + y) * XP_ + x) * C + c8 * 8) = z;
}

// ---------- pack: three fp32 NCHW -> one fp16 padded NHWC (B,130,130,768) ----------
__global__ __launch_bounds__(256) void pack_x(
    const float* __restrict__ f1, const float* __restrict__ f2,
    const float* __restrict__ f3, half_t* __restrict__ xcat) {
  __shared__ float tile[64][65];
  int bid = blockIdx.x;
  int t = bid % 24, by = bid / 24;
  int b = by >> 7, y = by & 127;
  int s = t / 8, t2 = t % 8;
  int x0 = (t2 & 1) * 64, c0 = (t2 >> 1) * 64;
  const float* f = (s == 0) ? f1 : ((s == 1) ? f2 : f3);
  int tid = threadIdx.x;
  int rx = tid & 63, rc = tid >> 6;
  const float* srcp = f + ((size_t)(b * 256 + c0)) * HW_ + (size_t)y * W_ + x0;
#pragma unroll
  for (int i = 0; i < 16; ++i) {
    int c = rc + i * 4;
    tile[c][rx] = srcp[(size_t)c * HW_ + rx];
  }
  __syncthreads();
#pragma unroll
  for (int it = 0; it < 2; ++it) {
    int task = tid + it * 256;
    int x = task & 63, c8 = task >> 6;
    h8v v;
#pragma unroll
    for (int j = 0; j < 8; ++j) v[j] = (half_t)tile[c8 * 8 + j][x];
    size_t pix = (size_t)(b * XP_ + y + 1) * XP_ + x0 + x + 1;
    *(h8v*)(xcat + pix * 768 + s * 256 + c0 + c8 * 8) = v;
  }
}

// ---------- weight transforms (all fused into one launch) ----------
__device__ __forceinline__ void wt_conv(const float* __restrict__ w,
                                        half_t* __restrict__ wt, int CO, int CI,
                                        int idx) {
  int CS = CI >> 6;
  int e = idx & 8191, tile = idx >> 13;
  int task = e >> 3, j = e & 7;
  int r = task >> 3, c8 = (task & 7) ^ (r & 7);
  int tpb = 9 * CS;
  int coblk = tile / tpb, within = tile - coblk * tpb;
  int dx = within % 3, q = within / 3;
  int cs = q % CS, g = q / CS;
  int t = g * 3 + dx;
  int co = coblk * 128 + r;
  int ci = cs * 64 + c8 * 8 + j;
  float v = (co < CO) ? w[((size_t)co * CI + ci) * 9 + t] : 0.f;
  wt[idx] = (half_t)v;
}
__device__ __forceinline__ void wt_c64(const float* __restrict__ w,
                                       half_t* __restrict__ wt, int idx) {
  int e = idx & 4095, tile = idx >> 12;
  int task = e >> 3, j = e & 7;
  int r = task >> 3, c8 = (task & 7) ^ (r & 7);
  int dx = tile % 3, q = tile / 3;
  int cs = q & 3, g = q >> 2;
  int t = g * 3 + dx;
  int ci = cs * 64 + c8 * 8 + j;
  float v = (r < 36) ? w[((size_t)r * 256 + ci) * 9 + t] : 0.f;
  wt[idx] = (half_t)v;
}
__device__ __forceinline__ void wt_256(const float* __restrict__ w,
                                       half_t* __restrict__ wt, int idx) {
  int e = idx & 16383, tile = idx >> 14;
  int task = e >> 3, j = e & 7;
  int r = task >> 3, c8 = (task & 7) ^ (r & 7);
  int cs = tile & 3, t = tile >> 2;
  int ci = cs * 64 + c8 * 8 + j;
  wt[idx] = (half_t)w[((size_t)r * 256 + ci) * 9 + t];
}
__device__ __forceinline__ void wt_fuse(const float* __restrict__ w,
                                        half_t* __restrict__ wt, int idx) {
  int e = idx & 8191, tile = idx >> 13;
  int task = e >> 3, j = e & 7;
  int r = task >> 3, c8 = (task & 7) ^ (r & 7);
  int cs = tile % 12, coblk = tile / 12;
  int co = coblk * 128 + r;
  int ci = cs * 64 + c8 * 8 + j;
  wt[idx] = (half_t)w[(size_t)co * 768 + ci];
}

__global__ __launch_bounds__(256) void wtrans_all(
    const float* __restrict__ w1, half_t* __restrict__ w1t,
    const float* __restrict__ w2, half_t* __restrict__ w2t,
    const float* __restrict__ w3, half_t* __restrict__ w3t,
    const float* __restrict__ wd2, half_t* __restrict__ wd2t,
    const float* __restrict__ wd3, half_t* __restrict__ wd3t,
    const float* __restrict__ wf, half_t* __restrict__ wft) {
  int bid = blockIdx.x, tid = threadIdx.x;
  if (bid < 6912)       wt_conv(w1, w1t, 256, 768, bid * 256 + tid);
  else if (bid < 9216)  wt_conv(w2, w2t, 256, 256, (bid - 6912) * 256 + tid);
  else if (bid < 9792)  wt_c64(w3, w3t, (bid - 9216) * 256 + tid);
  else if (bid < 12096) wt_256(wd2, wd2t, (bid - 9792) * 256 + tid);
  else if (bid < 14400) wt_256(wd3, wd3t, (bid - 12096) * 256 + tid);
  else                  wt_fuse(wf, wft, (bid - 14400) * 256 + tid);
}

// ---------- 3x3 conv, implicit GEMM, act-row sharing + counted vmcnt ----------
template <int CIN, bool RELU>
__global__ __launch_bounds__(256) void conv3x3(
    const half_t* __restrict__ in, const half_t* __restrict__ wt,
    const float* __restrict__ bias, half_t* __restrict__ outb) {
  constexpr int CS = CIN / 64;
  constexpr int NGI = 3 * CS;  // (ky, cs) act-tile count
  __shared__ __align__(16) half_t wl[2][8192];
  __shared__ __align__(16) half_t al[2][8704];  // 136 x 64
  int tid = threadIdx.x;
  int by = blockIdx.x;
  int b = by >> 7, y = by & 127;
  int co0 = blockIdx.y * 128;
  int w = tid >> 6, l = tid & 63, lr = l & 15, lg = l >> 4;
  int wr = (w >> 1) * 64, wc = (w & 1) * 64;
  f32x4 acc[4][4];
#pragma unroll
  for (int i = 0; i < 4; ++i)
#pragma unroll
    for (int j = 0; j < 4; ++j) acc[i][j] = zero4();

  const half_t* wbase = wt + (size_t)blockIdx.y * (9 * CS) * 8192;

  int ldsoff[4], aoff[4], ldsoff4, aoff4;
#pragma unroll
  for (int it = 0; it < 4; ++it) {
    int task = tid + it * 256;
    ldsoff[it] = task * 8;
    int r = task >> 3, c8 = (task & 7) ^ (r & 7);
    aoff[it] = r * CIN + c8 * 8;
  }
  {
    int task = 1024 + tid;
    ldsoff4 = task * 8;
    int r = task >> 3, c8 = (task & 7) ^ (r & 7);
    aoff4 = r * CIN + c8 * 8;
  }

  auto stage_w = [&](int s, int buf) {
    const half_t* wp = wbase + (size_t)s * 8192;
#pragma unroll
    for (int it = 0; it < 4; ++it)
      gl_lds16(wp + ldsoff[it], &wl[buf][ldsoff[it]]);
  };
  auto stage_a = [&](int gi, int buf) {
    int g = gi / CS, cs = gi - g * CS;
    const half_t* ap = in + ((size_t)(b * XP_ + y + g) * XP_) * CIN + cs * 64;
    if (tid < 64) gl_lds16(ap + aoff4, &al[buf][ldsoff4]);
#pragma unroll
    for (int it = 0; it < 4; ++it)
      gl_lds16(ap + aoff[it], &al[buf][ldsoff[it]]);
  };
  auto compute = [&](int dx, int wbuf, int abuf) {
    const half_t* wb = wl[wbuf];
    const half_t* ab = al[abuf];
    h8v af[4][2], bf[4][2];
#pragma unroll
    for (int cg = 0; cg < 4; ++cg)
#pragma unroll
      for (int kc = 0; kc < 2; ++kc)
        af[cg][kc] = *(const h8v*)(wb + swz(wr + 16 * cg + lr, 4 * kc + lg));
#pragma unroll
    for (int pg = 0; pg < 4; ++pg)
#pragma unroll
      for (int kc = 0; kc < 2; ++kc)
        bf[pg][kc] = *(const h8v*)(ab + swz(wc + 16 * pg + lr + dx, 4 * kc + lg));
    __builtin_amdgcn_s_setprio(1);
#pragma unroll
    for (int cg = 0; cg < 4; ++cg)
#pragma unroll
      for (int pg = 0; pg < 4; ++pg) {
        acc[cg][pg] = MFMA(af[cg][0], bf[pg][0], acc[cg][pg]);
        acc[cg][pg] = MFMA(af[cg][1], bf[pg][1], acc[cg][pg]);
      }
    __builtin_amdgcn_s_setprio(0);
  };

  stage_w(0, 0);
  stage_a(0, 0);
  for (int gi = 0; gi < NGI; ++gi) {
    int abuf = gi & 1;
    int s0 = 3 * gi;
    stage_w(s0 + 1, (s0 + 1) & 1);
    s_wait_vmcnt<4>();
    __builtin_amdgcn_s_barrier();
    compute(0, s0 & 1, abuf);
    __builtin_amdgcn_s_barrier();
    stage_w(s0 + 2, s0 & 1);
    s_wait_vmcnt<4>();
    __builtin_amdgcn_s_barrier();
    compute(1, (s0 + 1) & 1, abuf);
    __builtin_amdgcn_s_barrier();
    if (gi + 1 < NGI) {
      stage_w(s0 + 3, (s0 + 3) & 1);
      stage_a(gi + 1, abuf ^ 1);
      s_wait_vmcnt<8>();
    } else {
      s_wait_vmcnt<0>();
    }
    __builtin_amdgcn_s_barrier();
    compute(2, s0 & 1, abuf);
    __builtin_amdgcn_s_barrier();
  }
#pragma unroll
  for (int cg = 0; cg < 4; ++cg) {
    int co = co0 + wr + 16 * cg + 4 * lg;
    f32x4 bv = *(const f32x4*)(bias + co);
#pragma unroll
    for (int pg = 0; pg < 4; ++pg) {
      int px = wc + 16 * pg + lr;
      f32x4 v = acc[cg][pg];
#pragma unroll
      for (int r = 0; r < 4; ++r) {
        v[r] += bv[r];
        if (RELU) v[r] = fmaxf(v[r], 0.f);
      }
      size_t pix = (size_t)(b * XP_ + y + 1) * XP_ + px + 1;
      h4v pv;
#pragma unroll
      for (int r = 0; r < 4; ++r) pv[r] = (half_t)v[r];
      *(h4v*)(outb + pix * 256 + co) = pv;
    }
  }
}

// ---------- narrow 3x3 conv for the 36-co offset head (fp32 NHWC out) ----------
__global__ __launch_bounds__(256) void conv3_c64(
    const half_t* __restrict__ in, const half_t* __restrict__ wt,
    const float* __restrict__ bias, float* __restrict__ outf) {
  constexpr int CIN = 256, CS = 4, NGI = 12;
  __shared__ __align__(16) half_t wl[2][4096];
  __shared__ __align__(16) half_t al[2][8704];
  int tid = threadIdx.x;
  int by = blockIdx.x;
  int b = by >> 7, y = by & 127;
  int w = tid >> 6, l = tid & 63, lr = l & 15, lg = l >> 4;
  int wc = w * 32;
  f32x4 acc[4][2];
#pragma unroll
  for (int i = 0; i < 4; ++i)
#pragma unroll
    for (int j = 0; j < 2; ++j) acc[i][j] = zero4();

  int ldsW[2];
#pragma unroll
  for (int it = 0; it < 2; ++it) ldsW[it] = (tid + it * 256) * 8;
  int ldsoff[4], aoff[4], ldsoff4, aoff4;
#pragma unroll
  for (int it = 0; it < 4; ++it) {
    int task = tid + it * 256;
    ldsoff[it] = task * 8;
    int r = task >> 3, c8 = (task & 7) ^ (r & 7);
    aoff[it] = r * CIN + c8 * 8;
  }
  {
    int task = 1024 + tid;
    ldsoff4 = task * 8;
    int r = task >> 3, c8 = (task & 7) ^ (r & 7);
    aoff4 = r * CIN + c8 * 8;
  }

  auto stage_w = [&](int s, int buf) {
    const half_t* wp = wt + (size_t)s * 4096;
#pragma unroll
    for (int it = 0; it < 2; ++it)
      gl_lds16(wp + ldsW[it], &wl[buf][ldsW[it]]);
  };
  auto stage_a = [&](int gi, int buf) {
    int g = gi / CS, cs = gi - g * CS;
    const half_t* ap = in + ((size_t)(b * XP_ + y + g) * XP_) * CIN + cs * 64;
    if (tid < 64) gl_lds16(ap + aoff4, &al[buf][ldsoff4]);
#pragma unroll
    for (int it = 0; it < 4; ++it)
      gl_lds16(ap + aoff[it], &al[buf][ldsoff[it]]);
  };
  auto compute = [&](int dx, int wbuf, int abuf) {
    const half_t* wb = wl[wbuf];
    const half_t* ab = al[abuf];
    h8v af[4][2], bf[2][2];
#pragma unroll
    for (int cg = 0; cg < 4; ++cg)
#pragma unroll
      for (int kc = 0; kc < 2; ++kc)
        af[cg][kc] = *(const h8v*)(wb + swz(16 * cg + lr, 4 * kc + lg));
#pragma unroll
    for (int pg = 0; pg < 2; ++pg)
#pragma unroll
      for (int kc = 0; kc < 2; ++kc)
        bf[pg][kc] = *(const h8v*)(ab + swz(wc + 16 * pg + lr + dx, 4 * kc + lg));
    __builtin_amdgcn_s_setprio(1);
#pragma unroll
    for (int cg = 0; cg < 4; ++cg)
#pragma unroll
      for (int pg = 0; pg < 2; ++pg) {
        acc[cg][pg] = MFMA(af[cg][0], bf[pg][0], acc[cg][pg]);
        acc[cg][pg] = MFMA(af[cg][1], bf[pg][1], acc[cg][pg]);
      }
    __builtin_amdgcn_s_setprio(0);
  };

  stage_w(0, 0);
  stage_a(0, 0);
  for (int gi = 0; gi < NGI; ++gi) {
    int abuf = gi & 1;
    int s0 = 3 * gi;
    stage_w(s0 + 1, (s0 + 1) & 1);
    s_wait_vmcnt<2>();
    __builtin_amdgcn_s_barrier();
    compute(0, s0 & 1, abuf);
    __builtin_amdgcn_s_barrier();
    stage_w(s0 + 2, s0 & 1);
    s_wait_vmcnt<2>();
    __builtin_amdgcn_s_barrier();
    compute(1, (s0 + 1) & 1, abuf);
    __builtin_amdgcn_s_barrier();
    if (gi + 1 < NGI) {
      stage_w(s0 + 3, (s0 + 3) & 1);
      stage_a(gi + 1, abuf ^ 1);
      s_wait_vmcnt<6>();
    } else {
      s_wait_vmcnt<0>();
    }
    __builtin_amdgcn_s_barrier();
    compute(2, s0 & 1, abuf);
    __builtin_amdgcn_s_barrier();
  }
#pragma unroll
  for (int cg = 0; cg < 4; ++cg) {
    int co = 16 * cg + 4 * lg;
    if (co >= 36) continue;
    f32x4 bv = *(const f32x4*)(bias + co);
#pragma unroll
    for (int pg = 0; pg < 2; ++pg) {
      int px = wc + 16 * pg + lr;
      f32x4 v = acc[cg][pg];
#pragma unroll
      for (int r = 0; r < 4; ++r) v[r] += bv[r];
      size_t pix = (size_t)(b * H_ + y) * W_ + px;
      *(f32x4*)(outf + pix * 36 + co) = v;
    }
  }
}

// ---------- deformable conv (r6 structure + 2-deep gather prefetch) ----------
// 512 threads, 8 waves as 4co x 2px, each 64co x 64px, acc[4][4].
// All 9 taps' bilinear coeffs precomputed in prologue (LDS, 27KB).
// Corner gathers prefetched TWO steps ahead into named reg buffers cvA/cvB
// (loop unrolled x2 so every buffer index is compile-time; rule #20).
__global__ __launch_bounds__(512) void dcn(
    const half_t* __restrict__ xcat, const float* __restrict__ off,
    const half_t* __restrict__ wt2, const half_t* __restrict__ wt3,
    half_t* __restrict__ out2, half_t* __restrict__ out3) {
  __shared__ __align__(16) half_t wl[2][16384];  // 64KB
  __shared__ __align__(16) half_t al[2][8192];   // 32KB
  __shared__ int caddr[9][128][4];               // 18KB
  __shared__ half_t chw[9][128][4];              // 9KB  -> 123KB total
  int gy = blockIdx.y;
  const half_t* wt = gy ? wt3 : wt2;
  half_t* outb = gy ? out3 : out2;
  int cbase = 256 + (gy << 8);
  int obase = 18 * gy;
  int tid = threadIdx.x;
  int bx = blockIdx.x;
  int by = ((bx & 7) << 5) | (bx >> 3);  // XCD-chunked (256 % 8 == 0, bijective)
  int b = by >> 7, y = by & 127;
  int w = tid >> 6, l = tid & 63, lr = l & 15, lg = l >> 4;
  int wr = (w >> 1) * 64, wc = (w & 1) * 64;
  size_t rowpix = (size_t)(b * H_ + y) * W_;
  f32x4 acc[4][4];
#pragma unroll
  for (int i = 0; i < 4; ++i)
#pragma unroll
    for (int j = 0; j < 4; ++j) acc[i][j] = zero4();

  // prologue: coeffs for ALL 9 taps, all threads (1152 entries)
  for (int e = tid; e < 1152; e += 512) {
    int t = e >> 7, px = e & 127;
    const float* op = off + (rowpix + px) * 36 + obase + 2 * t;
    float dy = op[0], dx = op[1];
    float ysf = (float)(y + (t / 3) - 1) + dy;
    float xsf = (float)(px + (t % 3) - 1) + dx;
    float y0f = floorf(ysf), x0f = floorf(xsf);
    float fy = ysf - y0f, fx = xsf - x0f;
    int y0 = (int)y0f, x0 = (int)x0f;
#pragma unroll
    for (int c = 0; c < 4; ++c) {
      int iy = y0 + (c >> 1), ix = x0 + (c & 1);
      float wc2 = ((c >> 1) ? fy : 1.f - fy) * ((c & 1) ? fx : 1.f - fx);
      bool valid = (iy >= 0) && (iy < H_) && (ix >= 0) && (ix < W_);
      int cy = iy < 0 ? 0 : (iy > H_ - 1 ? H_ - 1 : iy);
      int cx = ix < 0 ? 0 : (ix > W_ - 1 ? W_ - 1 : ix);
      caddr[t][px][c] = ((b * XP_ + cy + 1) * XP_ + cx + 1) * 768 + cbase;
      chw[t][px][c] = (half_t)(valid ? wc2 : 0.f);
    }
  }
  __syncthreads();

  auto blendload = [&](int s, h8v (&cv)[2][4]) {
    int t = s >> 2;
    int c0 = (s & 3) * 64;
#pragma unroll
    for (int it = 0; it < 2; ++it) {
      int task = tid + it * 512;
      int px = task >> 3;
      int cc = c0 + (task & 7) * 8;
#pragma unroll
      for (int c = 0; c < 4; ++c)
        cv[it][c] = *(const h8v*)(xcat + caddr[t][px][c] + cc);
    }
  };
  auto blendwrite = [&](int s, int buf, h8v (&cv)[2][4]) {
    int t = s >> 2;
#pragma unroll
    for (int it = 0; it < 2; ++it) {
      int task = tid + it * 512;
      int px = task >> 3, c8 = task & 7;
      h8v av = cv[it][0] * splat8(chw[t][px][0]);
      av += cv[it][1] * splat8(chw[t][px][1]);
      av += cv[it][2] * splat8(chw[t][px][2]);
      av += cv[it][3] * splat8(chw[t][px][3]);
      *(h8v*)(&al[buf][swz(px, c8)]) = av;
    }
  };
  auto stagew = [&](int s, int buf) {
    const half_t* wp = wt + (size_t)s * 16384;
#pragma unroll
    for (int it = 0; it < 4; ++it) {
      int task = tid + it * 512;
      gl_lds16(wp + task * 8, &wl[buf][task * 8]);
    }
  };
  auto gemm_step = [&](const half_t* wb, const half_t* ab) {
    h8v af[4][2], bf[4][2];
#pragma unroll
    for (int cg = 0; cg < 4; ++cg)
#pragma unroll
      for (int kc = 0; kc < 2; ++kc)
        af[cg][kc] = *(const h8v*)(wb + swz(wr + 16 * cg + lr, 4 * kc + lg));
#pragma unroll
    for (int pg = 0; pg < 4; ++pg)
#pragma unroll
      for (int kc = 0; kc < 2; ++kc)
        bf[pg][kc] = *(const h8v*)(ab + swz(wc + 16 * pg + lr, 4 * kc + lg));
    __builtin_amdgcn_s_setprio(1);
#pragma unroll
    for (int cg = 0; cg < 4; ++cg)
#pragma unroll
      for (int pg = 0; pg < 4; ++pg) {
        acc[cg][pg] = MFMA(af[cg][0], bf[pg][0], acc[cg][pg]);
        acc[cg][pg] = MFMA(af[cg][1], bf[pg][1], acc[cg][pg]);
      }
    __builtin_amdgcn_s_setprio(0);
  };

  h8v cvA[2][4], cvB[2][4];
  // prologue pipeline fill
  stagew(0, 0);
  blendload(0, cvA);
  blendwrite(0, 0, cvA);  // cvA wait also retires stagew(0) (issued first)
  blendload(1, cvB);      // gather for step 1, consumed at s=0's blendwrite
  __syncthreads();

  for (int ss = 0; ss < 18; ++ss) {
    int s0 = 2 * ss;        // even step: cur=0, nxt=1
    stagew(s0 + 1, 1);
    if (s0 + 2 < 36) blendload(s0 + 2, cvA);
    gemm_step(wl[0], al[0]);
    blendwrite(s0 + 1, 1, cvB);  // cvB loaded a full step ago
    if (s0 + 2 < 36) s_wait_vmcnt<8>(); else s_wait_vmcnt<0>();
    __builtin_amdgcn_s_barrier();

    int s1 = s0 + 1;        // odd step: cur=1, nxt=0
    if (s1 + 1 < 36) stagew(s1 + 1, 0);
    if (s1 + 2 < 36) blendload(s1 + 2, cvB);
    gemm_step(wl[1], al[1]);
    if (s1 + 1 < 36) blendwrite(s1 + 1, 0, cvA);
    if (s1 + 2 < 36) s_wait_vmcnt<8>(); else s_wait_vmcnt<0>();
    __builtin_amdgcn_s_barrier();
  }
#pragma unroll
  for (int cg = 0; cg < 4; ++cg) {
    int co = wr + 16 * cg + 4 * lg;
#pragma unroll
    for (int pg = 0; pg < 4; ++pg) {
      int px = wc + 16 * pg + lr;
      size_t pix = rowpix + px;
      f32x4 v = acc[cg][pg];
      h4v pv;
#pragma unroll
      for (int r = 0; r < 4; ++r) pv[r] = (half_t)v[r];
      *(h4v*)(outb + pix * 256 + co) = pv;
    }
  }
}

// ---------- 1x1 fuse conv: 2-phase + counted vmcnt, out fp32 NCHW ----------
__global__ __launch_bounds__(256) void fuse1x1(
    const half_t* __restrict__ xcat, const half_t* __restrict__ al2,
    const half_t* __restrict__ al3, const half_t* __restrict__ wt,
    const float* __restrict__ bias, float* __restrict__ out) {
  __shared__ __align__(16) half_t wl[2][8192];
  __shared__ __align__(16) half_t al[2][8192];
  int tid = threadIdx.x;
  int by = blockIdx.x;
  int b = by >> 7, y = by & 127;
  int co0 = blockIdx.y * 128;
  int w = tid >> 6, l = tid & 63, lr = l & 15, lg = l >> 4;
  int pxb = (w >> 1) * 64, cob = (w & 1) * 64;
  f32x4 acc[4][4];  // [pg][cg]
#pragma unroll
  for (int i = 0; i < 4; ++i)
#pragma unroll
    for (int j = 0; j < 4; ++j) acc[i][j] = zero4();

  const half_t* wbase = wt + (size_t)blockIdx.y * 12 * 8192;
  size_t rowpix = (size_t)(b * H_ + y) * W_;
  const half_t* xrow = xcat + ((size_t)(b * XP_ + y + 1) * XP_ + 1) * 768;

  int woff[4], rr[4], c8x8[4];
#pragma unroll
  for (int it = 0; it < 4; ++it) {
    int task = tid + it * 256;
    woff[it] = task * 8;
    rr[it] = task >> 3;
    c8x8[it] = (((task & 7) ^ (rr[it] & 7))) * 8;
  }

  auto stage = [&](int cs, int buf) {
    const half_t* wp = wbase + (size_t)cs * 8192;
#pragma unroll
    for (int it = 0; it < 4; ++it) gl_lds16(wp + woff[it], &wl[buf][woff[it]]);
#pragma unroll
    for (int it = 0; it < 4; ++it) {
      int kk = cs * 64 + c8x8[it];
      const half_t* sp;
      if (kk < 256) sp = xrow + (size_t)rr[it] * 768 + kk;
      else if (kk < 512) sp = al2 + (rowpix + rr[it]) * 256 + (kk - 256);
      else sp = al3 + (rowpix + rr[it]) * 256 + (kk - 512);
      gl_lds16(sp, &al[buf][woff[it]]);
    }
  };

  stage(0, 0);
  for (int cs = 0; cs < 12; ++cs) {
    int cur = cs & 1;
    if (cs + 1 < 12) {
      stage(cs + 1, cur ^ 1);
      s_wait_vmcnt<8>();
    } else {
      s_wait_vmcnt<0>();
    }
    __builtin_amdgcn_s_barrier();
    const half_t* wb = wl[cur];
    const half_t* ab = al[cur];
    h8v af[4][2], bf[4][2];
#pragma unroll
    for (int pg = 0; pg < 4; ++pg)
#pragma unroll
      for (int kc = 0; kc < 2; ++kc)
        af[pg][kc] = *(const h8v*)(ab + swz(pxb + 16 * pg + lr, 4 * kc + lg));
#pragma unroll
    for (int cg = 0; cg < 4; ++cg)
#pragma unroll
      for (int kc = 0; kc < 2; ++kc)
        bf[cg][kc] = *(const h8v*)(wb + swz(cob + 16 * cg + lr, 4 * kc + lg));
    __builtin_amdgcn_s_setprio(1);
#pragma unroll
    for (int pg = 0; pg < 4; ++pg)
#pragma unroll
      for (int cg = 0; cg < 4; ++cg) {
        acc[pg][cg] = MFMA(af[pg][0], bf[cg][0], acc[pg][cg]);
        acc[pg][cg] = MFMA(af[pg][1], bf[cg][1], acc[pg][cg]);
      }
    __builtin_amdgcn_s_setprio(0);
    __builtin_amdgcn_s_barrier();
  }
#pragma unroll
  for (int pg = 0; pg < 4; ++pg)
#pragma unroll
    for (int cg = 0; cg < 4; ++cg) {
      int px = pxb + 16 * pg + 4 * lg;
      int co = co0 + cob + 16 * cg + lr;
      float bb = bias[co];
      f32x4 v = acc[pg][cg];
#pragma unroll
      for (int r = 0; r < 4; ++r) v[r] += bb;
      *(f32x4*)(out + ((size_t)(b * 256 + co)) * HW_ + (size_t)y * W_ + px) = v;
    }
}

extern "C" void kernel_launch(void* const* d_in, const int* in_sizes, int n_in,
                              void* d_out, int out_size, void* d_ws, size_t ws_size,
                              hipStream_t stream) {
  (void)in_sizes; (void)n_in; (void)out_size; (void)ws_size;
  const float* ft1 = (const float*)d_in[0];
  const float* ft2 = (const float*)d_in[1];
  const float* ft3 = (const float*)d_in[2];
  const float* w1 = (const float*)d_in[3];
  const float* b1 = (const float*)d_in[4];
  const float* w2 = (const float*)d_in[5];
  const float* b2 = (const float*)d_in[6];
  const float* w3 = (const float*)d_in[7];
  const float* b3 = (const float*)d_in[8];
  const float* wd2 = (const float*)d_in[9];
  const float* wd3 = (const float*)d_in[10];
  const float* wf = (const float*)d_in[11];
  const float* bfu = (const float*)d_in[12];

  char* p = (char*)d_ws;
  half_t* xcat = (half_t*)p; p += (size_t)B_ * XP_ * XP_ * 768 * 2;  // 51.9 MB
  half_t* h1p = (half_t*)p;  p += (size_t)B_ * XP_ * XP_ * 256 * 2;  // 17.3 MB
  half_t* h2p = (half_t*)p;  p += (size_t)B_ * XP_ * XP_ * 256 * 2;  // 17.3 MB
  float* off = (float*)p;    p += (size_t)B_ * HW_ * 36 * 4;         // 4.7 MB
  half_t* w1t = (half_t*)p;  p += (size_t)2 * 9 * 12 * 8192 * 2;
  half_t* w2t = (half_t*)p;  p += (size_t)2 * 9 * 4 * 8192 * 2;
  half_t* w3t = (half_t*)p;  p += (size_t)36 * 4096 * 2;
  half_t* wd2t = (half_t*)p; p += (size_t)36 * 16384 * 2;
  half_t* wd3t = (half_t*)p; p += (size_t)36 * 16384 * 2;
  half_t* wft = (half_t*)p;  p += (size_t)2 * 12 * 8192 * 2;         // ~99.4 MB total
  half_t* al2 = h1p;  // h1p dead after conv2
  half_t* al3 = h2p;  // h2p dead after conv3

  zeropad_all<<<645, 256, 0, stream>>>(xcat, h1p, h2p);
  pack_x<<<24 * B_ * H_, 256, 0, stream>>>(ft1, ft2, ft3, xcat);
  wtrans_all<<<15168, 256, 0, stream>>>(w1, w1t, w2, w2t, w3, w3t,
                                        wd2, wd2t, wd3, wd3t, wf, wft);

  conv3x3<768, true><<<dim3(B_ * H_, 2), 256, 0, stream>>>(xcat, w1t, b1, h1p);
  conv3x3<256, true><<<dim3(B_ * H_, 2), 256, 0, stream>>>(h1p, w2t, b2, h2p);
  conv3_c64<<<dim3(B_ * H_), 256, 0, stream>>>(h2p, w3t, b3, off);
  dcn<<<dim3(B_ * H_, 2), 512, 0, stream>>>(xcat, off, wd2t, wd3t, al2, al3);
  fuse1x1<<<dim3(B_ * H_, 2), 256, 0, stream>>>(xcat, al2, al3, wft, bfu, (float*)d_out);
}